// Round 1
// baseline (1505.050 us; speedup 1.0000x reference)
//
#include <hip/hip_runtime.h>

#define Sdim 1024
#define Bdim 8
#define Edim 512
#define Hdim 8
#define Ddim 64
#define Ndim 64   // B*H
#define Mdim 8192 // S*B

typedef __attribute__((ext_vector_type(8))) short short8;  // 8 bf16 = 4 VGPRs (MFMA A/B frag)
typedef __attribute__((ext_vector_type(4))) float f32x4;   // MFMA C/D frag
typedef __attribute__((ext_vector_type(4))) short short4v; // 4 bf16 = 8B store

__device__ inline unsigned short f2bf(float x) {  // RNE float->bf16 (finite inputs)
    unsigned int u = __float_as_uint(x);
    u += 0x7FFFu + ((u >> 16) & 1u);
    return (unsigned short)(u >> 16);
}

__device__ inline short8 f2bf8(const float4 a, const float4 b) {
    short8 f;
    f[0] = (short)f2bf(a.x); f[1] = (short)f2bf(a.y);
    f[2] = (short)f2bf(a.z); f[3] = (short)f2bf(a.w);
    f[4] = (short)f2bf(b.x); f[5] = (short)f2bf(b.y);
    f[6] = (short)f2bf(b.z); f[7] = (short)f2bf(b.w);
    return f;
}

// ---------------------------------------------------------------------------
// Mask dtype detector: byte-packed bools viewed as int32 give values >1.
// ---------------------------------------------------------------------------
__global__ void detect_mask(const unsigned int* __restrict__ m, int* __restrict__ flag) {
    __shared__ int s_any;
    if (threadIdx.x == 0) s_any = 0;
    __syncthreads();
    int bad = 0;
    for (int i = threadIdx.x; i < 4096; i += blockDim.x)
        if (m[i] > 1u) bad = 1;
    if (bad) s_any = 1;
    __syncthreads();
    if (threadIdx.x == 0) *flag = s_any;
}

// ---------------------------------------------------------------------------
// Tiled fp32 GEMM: C[m,o] = sum_k A[m,k]*W[o,k] + bias[o]
// MODE 0: bf16 output scattered to [n,s,d]   (q,k,v)
// MODE 1: fp32 [m,o] output + residual add   (out proj)
// ---------------------------------------------------------------------------
template <int MODE>
__global__ __launch_bounds__(256) void proj_gemm(const float* __restrict__ A,
                                                 const float* __restrict__ W,
                                                 const float* __restrict__ bias,
                                                 const float* __restrict__ res,
                                                 void* __restrict__ outv) {
    __shared__ float As[16][68];
    __shared__ float Ws[16][68];
    const int t = threadIdx.x;
    const int tx = t & 15, ty = t >> 4;
    const int m0 = blockIdx.x * 64;
    const int n0 = blockIdx.y * 64;
    float acc[4][4] = {};
    const int lr = t >> 2;
    const int lk = (t & 3) * 4;
    for (int k0 = 0; k0 < Edim; k0 += 16) {
        const float4 av = *(const float4*)(A + (size_t)(m0 + lr) * Edim + k0 + lk);
        const float4 wv = *(const float4*)(W + (size_t)(n0 + lr) * Edim + k0 + lk);
        As[lk + 0][lr] = av.x; As[lk + 1][lr] = av.y; As[lk + 2][lr] = av.z; As[lk + 3][lr] = av.w;
        Ws[lk + 0][lr] = wv.x; Ws[lk + 1][lr] = wv.y; Ws[lk + 2][lr] = wv.z; Ws[lk + 3][lr] = wv.w;
        __syncthreads();
#pragma unroll
        for (int kk = 0; kk < 16; ++kk) {
            float a[4], b[4];
#pragma unroll
            for (int ii = 0; ii < 4; ++ii) a[ii] = As[kk][ty + 16 * ii];
#pragma unroll
            for (int jj = 0; jj < 4; ++jj) b[jj] = Ws[kk][tx + 16 * jj];
#pragma unroll
            for (int ii = 0; ii < 4; ++ii)
#pragma unroll
                for (int jj = 0; jj < 4; ++jj) acc[ii][jj] += a[ii] * b[jj];
        }
        __syncthreads();
    }
#pragma unroll
    for (int ii = 0; ii < 4; ++ii) {
        const int m = m0 + ty + 16 * ii;
#pragma unroll
        for (int jj = 0; jj < 4; ++jj) {
            const int o = n0 + tx + 16 * jj;
            float v = acc[ii][jj] + bias[o];
            if (MODE == 1) {
                ((float*)outv)[(size_t)m * Edim + o] = v + res[(size_t)m * Edim + o];
            } else {
                const int s = m / Bdim, b = m % Bdim;
                const int h = o >> 6, d = o & 63;
                const size_t f = (((size_t)(b * Hdim + h) * Sdim) + s) * Ddim + d;
                ((unsigned short*)outv)[f] = f2bf(v);
            }
        }
    }
}

// ---------------------------------------------------------------------------
// Transpose v: vh bf16 [n][s][64] -> vt bf16 [n][64][s]  (B-operand for pv_v).
// XOR swizzle col ^= ((d>>4)&3)<<3 keeps LDS writes ~2-way conflict and read
// rows 16B aligned (pad 72: 144B row stride, mult of 16).
// ---------------------------------------------------------------------------
__global__ __launch_bounds__(256) void transpose_v(const unsigned short* __restrict__ vh,
                                                   unsigned short* __restrict__ vt) {
    __shared__ unsigned short Ls[64][72];
    const int n = blockIdx.y;
    const int s0 = blockIdx.x * 64;
    const int t = threadIdx.x;
    const int sr = t >> 2;
    const int dc = (t & 3) * 16;
    const short8* src = (const short8*)(vh + ((size_t)n * Sdim + s0 + sr) * Ddim + dc);
    const short8 a0 = src[0], a1 = src[1];
#pragma unroll
    for (int q = 0; q < 8; ++q) {
        const int d = dc + q;
        Ls[d][sr ^ ((((d) >> 4) & 3) << 3)] = (unsigned short)a0[q];
    }
#pragma unroll
    for (int q = 0; q < 8; ++q) {
        const int d = dc + 8 + q;
        Ls[d][sr ^ ((((d) >> 4) & 3) << 3)] = (unsigned short)a1[q];
    }
    __syncthreads();
    const int d = t >> 2;
    const int cc = (t & 3) * 16;
    const int x = ((d >> 4) & 3) << 3;
    const short8 o0 = *(const short8*)&Ls[d][cc ^ x];
    const short8 o1 = *(const short8*)&Ls[d][(cc + 8) ^ x];
    short8* dst = (short8*)(vt + ((size_t)n * Ddim + d) * Sdim + s0 + cc);
    dst[0] = o0; dst[1] = o1;
}

// ---------------------------------------------------------------------------
// MFMA logits: attn[n,i,j] = 0.125*(qk + bias), masked -> -3e38. (unchanged)
// ---------------------------------------------------------------------------
__global__ __launch_bounds__(256) void logits_mfma(const unsigned short* __restrict__ qh,
                                                   const unsigned short* __restrict__ kh,
                                                   const float* __restrict__ ek,
                                                   const unsigned char* __restrict__ mask8,
                                                   const int* __restrict__ flag,
                                                   float* __restrict__ attn) {
    __shared__ float bias_s[16 * 273 + 16];
    const int t = threadIdx.x;
    const int wave = t >> 6, lane = t & 63;
    const int quad = lane >> 4, l15 = lane & 15;
    const int i0 = blockIdx.y * 16;
    const int j0 = blockIdx.x * 16;
    const bool bmode = (*flag != 0);

    short8 ekf[4][2];
#pragma unroll
    for (int jj = 0; jj < 4; ++jj) {
        const int j = j0 + wave * 4 + jj;
#pragma unroll
        for (int kk = 0; kk < 2; ++kk) {
            const float4* p = (const float4*)(ek + ((size_t)j * Sdim + (i0 + l15)) * Ddim + kk * 32 + quad * 8);
            ekf[jj][kk] = f2bf8(p[0], p[1]);
        }
    }

    for (int n0 = 0; n0 < Ndim; n0 += 16) {
#pragma unroll
        for (int jj = 0; jj < 4; ++jj) {
            const int j = j0 + wave * 4 + jj;
            f32x4 acc = {0.f, 0.f, 0.f, 0.f};
#pragma unroll
            for (int kk = 0; kk < 2; ++kk) {
                const short8 b = *(const short8*)(qh + ((size_t)(n0 + l15) * Sdim + j) * Ddim + kk * 32 + quad * 8);
                acc = __builtin_amdgcn_mfma_f32_16x16x32_bf16(ekf[jj][kk], b, acc, 0, 0, 0);
            }
            const int jl = wave * 4 + jj;
#pragma unroll
            for (int r = 0; r < 4; ++r)
                bias_s[(quad * 4 + r) * 273 + jl * 17 + l15] = acc[r];
        }
        __syncthreads();
#pragma unroll
        for (int nn = 0; nn < 4; ++nn) {
            const int nl = wave * 4 + nn;
            const int n = n0 + nl;
            f32x4 acc = {0.f, 0.f, 0.f, 0.f};
#pragma unroll
            for (int kk = 0; kk < 2; ++kk) {
                const short8 a = *(const short8*)(qh + ((size_t)n * Sdim + (i0 + l15)) * Ddim + kk * 32 + quad * 8);
                const short8 b = *(const short8*)(kh + ((size_t)n * Sdim + (j0 + l15)) * Ddim + kk * 32 + quad * 8);
                acc = __builtin_amdgcn_mfma_f32_16x16x32_bf16(a, b, acc, 0, 0, 0);
            }
#pragma unroll
            for (int r = 0; r < 4; ++r) {
                const int il = quad * 4 + r;
                const int i = i0 + il;
                const int j = j0 + l15;
                const float bias = bias_s[il * 273 + l15 * 17 + nl];
                const size_t f = ((size_t)n * Sdim + i) * Sdim + j;
                const bool msk = bmode ? (mask8[f] != 0) : (((const int*)mask8)[f] != 0);
                const float v = (acc[r] + bias) * 0.125f;
                attn[f] = msk ? -3.0e38f : v;
            }
        }
        __syncthreads();
    }
}

// ---------------------------------------------------------------------------
// Row softmax over j (1024). PMODE 1: write bf16 P (attn left as raw logits).
// PMODE 0: normalize fp32 in place (ws fallback).
// ---------------------------------------------------------------------------
template <int PMODE>
__global__ __launch_bounds__(256) void softmax_kernel(float* __restrict__ attn,
                                                      unsigned short* __restrict__ P) {
    const size_t base = (size_t)blockIdx.x * Sdim;
    const int t = threadIdx.x;
    float4 x = *(const float4*)(attn + base + t * 4);
    float m = fmaxf(fmaxf(x.x, x.y), fmaxf(x.z, x.w));
#pragma unroll
    for (int off = 32; off > 0; off >>= 1) m = fmaxf(m, __shfl_down(m, off));
    __shared__ float red[4];
    __shared__ float red2[4];
    if ((t & 63) == 0) red[t >> 6] = m;
    __syncthreads();
    m = fmaxf(fmaxf(red[0], red[1]), fmaxf(red[2], red[3]));
    x.x = __expf(x.x - m); x.y = __expf(x.y - m);
    x.z = __expf(x.z - m); x.w = __expf(x.w - m);
    float s = x.x + x.y + x.z + x.w;
#pragma unroll
    for (int off = 32; off > 0; off >>= 1) s += __shfl_down(s, off);
    if ((t & 63) == 0) red2[t >> 6] = s;
    __syncthreads();
    s = red2[0] + red2[1] + red2[2] + red2[3];
    const float inv = (s > 0.0f) ? (1.0f / s) : 0.0f;
    x.x *= inv; x.y *= inv; x.z *= inv; x.w *= inv;
    if (PMODE) {
        short4v o;
        o[0] = (short)f2bf(x.x); o[1] = (short)f2bf(x.y);
        o[2] = (short)f2bf(x.z); o[3] = (short)f2bf(x.w);
        *(short4v*)(P + base + t * 4) = o;
    } else {
        *(float4*)(attn + base + t * 4) = x;
    }
}

// ---------------------------------------------------------------------------
// pv_v: ctx[i,d] (per n) = P[n,i,:] x v[n,:,:]  as MFMA GEMM.
// A = P (bf16, j contiguous -> direct frag loads), B = vt[n][d][j].
// Grid (n=64, i-tiles of 64). Wave w owns i-sub w*16, 4 d-tiles.
// ---------------------------------------------------------------------------
template <int PMODE>
__global__ __launch_bounds__(256) void pv_v_mfma(const void* __restrict__ Pv,
                                                 const unsigned short* __restrict__ vt,
                                                 float* __restrict__ ctx) {
    const int n = blockIdx.x;
    const int i0 = blockIdx.y * 64;
    const int t = threadIdx.x;
    const int wave = t >> 6, lane = t & 63;
    const int quad = lane >> 4, l15 = lane & 15;
    const size_t arow = ((size_t)n * Sdim + (i0 + wave * 16 + l15)) * Sdim;
    f32x4 acc[4] = {};
#pragma unroll 2
    for (int j0 = 0; j0 < Sdim; j0 += 32) {
        short8 a;
        if (PMODE) {
            a = *(const short8*)((const unsigned short*)Pv + arow + j0 + quad * 8);
        } else {
            const float4* pf = (const float4*)((const float*)Pv + arow + j0 + quad * 8);
            a = f2bf8(pf[0], pf[1]);
        }
#pragma unroll
        for (int dt = 0; dt < 4; ++dt) {
            const short8 b = *(const short8*)(vt + ((size_t)n * Ddim + dt * 16 + l15) * Sdim + j0 + quad * 8);
            acc[dt] = __builtin_amdgcn_mfma_f32_16x16x32_bf16(a, b, acc[dt], 0, 0, 0);
        }
    }
    const int bb = n >> 3, hh = n & 7;
    const int ibase = i0 + wave * 16 + quad * 4;
#pragma unroll
    for (int dt = 0; dt < 4; ++dt)
#pragma unroll
        for (int r = 0; r < 4; ++r)
            ctx[((size_t)((ibase + r) * Bdim + bb)) * Edim + hh * Ddim + dt * 16 + l15] = acc[dt][r];
}

// ---------------------------------------------------------------------------
// pv_ev: ctx[n,d] (per i) += P[:,i,:] x ev[i,:,:]  as MFMA GEMM.
// ev[i] is read ONCE from HBM (was 64x over-fetched), transposed fp32->bf16
// in LDS per 64-j tile. XOR swizzle (col ^= dt<<3) keeps ds_writes ~2-way
// and ds_read_b128 rows 16B-aligned. Each block owns a unique i -> rmw safe.
// ---------------------------------------------------------------------------
template <int PMODE>
__global__ __launch_bounds__(256) void pv_ev_mfma(const void* __restrict__ Pv,
                                                  const float* __restrict__ ev,
                                                  float* __restrict__ ctx) {
    __shared__ unsigned short Ls[64][72];
    const int i = blockIdx.x;
    const int t = threadIdx.x;
    const int wave = t >> 6, lane = t & 63;
    const int quad = lane >> 4, l15 = lane & 15;
    const int jr = t >> 2;
    const int dc = (t & 3) * 16;
    f32x4 acc[4] = {};
    for (int j0 = 0; j0 < Sdim; j0 += 64) {
        // issue global loads before the barrier (latency hides under the wait)
        const float4* src = (const float4*)(ev + ((size_t)i * Sdim + j0 + jr) * Ddim + dc);
        const float4 e0 = src[0], e1 = src[1], e2 = src[2], e3 = src[3];
        __syncthreads();  // previous tile's LDS reads complete
        const float vals[16] = {e0.x, e0.y, e0.z, e0.w, e1.x, e1.y, e1.z, e1.w,
                                e2.x, e2.y, e2.z, e2.w, e3.x, e3.y, e3.z, e3.w};
#pragma unroll
        for (int q = 0; q < 16; ++q) {
            const int d = dc + q;
            Ls[d][jr ^ (((d >> 4) & 3) << 3)] = f2bf(vals[q]);
        }
        __syncthreads();
#pragma unroll
        for (int kk = 0; kk < 2; ++kk) {
            short8 a;
            const size_t poff = ((size_t)(wave * 16 + l15) * Sdim + i) * Sdim + j0 + kk * 32 + quad * 8;
            if (PMODE) {
                a = *(const short8*)((const unsigned short*)Pv + poff);
            } else {
                const float4* pf = (const float4*)((const float*)Pv + poff);
                a = f2bf8(pf[0], pf[1]);
            }
#pragma unroll
            for (int dt = 0; dt < 4; ++dt) {
                const short8 b = *(const short8*)&Ls[dt * 16 + l15][(kk * 32 + quad * 8) ^ (dt << 3)];
                acc[dt] = __builtin_amdgcn_mfma_f32_16x16x32_bf16(a, b, acc[dt], 0, 0, 0);
            }
        }
    }
    const int nbase = wave * 16 + quad * 4;
#pragma unroll
    for (int dt = 0; dt < 4; ++dt)
#pragma unroll
        for (int r = 0; r < 4; ++r) {
            const int n = nbase + r;
            const int bb = n >> 3, hh = n & 7;
            float* p = ctx + ((size_t)(i * Bdim + bb)) * Edim + hh * Ddim + dt * 16 + l15;
            *p += acc[dt][r];
        }
}

// ---------------------------------------------------------------------------
// LayerNorm over last dim (512), in place on x (= d_out).
// ---------------------------------------------------------------------------
__global__ __launch_bounds__(256) void ln_kernel(float* __restrict__ x,
                                                 const float* __restrict__ gamma,
                                                 const float* __restrict__ beta) {
    const int m = blockIdx.x;
    const int t = threadIdx.x;
    float2 v = *(const float2*)(x + (size_t)m * Edim + t * 2);
    float s = v.x + v.y;
    float ss = v.x * v.x + v.y * v.y;
#pragma unroll
    for (int off = 32; off > 0; off >>= 1) {
        s += __shfl_down(s, off);
        ss += __shfl_down(ss, off);
    }
    __shared__ float rs[4], rss[4];
    if ((t & 63) == 0) { rs[t >> 6] = s; rss[t >> 6] = ss; }
    __syncthreads();
    s = rs[0] + rs[1] + rs[2] + rs[3];
    ss = rss[0] + rss[1] + rss[2] + rss[3];
    const float mean = s * (1.0f / Edim);
    const float var = ss * (1.0f / Edim) - mean * mean;
    const float rstd = rsqrtf(var + 1e-5f);
    const int o = t * 2;
    const float2 g = *(const float2*)(gamma + o);
    const float2 bb = *(const float2*)(beta + o);
    float2 out;
    out.x = g.x * (v.x - mean) * rstd + bb.x;
    out.y = g.y * (v.y - mean) * rstd + bb.y;
    *(float2*)(x + (size_t)m * Edim + o) = out;
}

extern "C" void kernel_launch(void* const* d_in, const int* in_sizes, int n_in,
                              void* d_out, int out_size, void* d_ws, size_t ws_size,
                              hipStream_t stream) {
    const float* query = (const float*)d_in[0];
    const float* key = (const float*)d_in[1];
    const float* value = (const float*)d_in[2];
    const float* ek = (const float*)d_in[3];
    const float* evl = (const float*)d_in[4];
    const unsigned char* mask = (const unsigned char*)d_in[5];
    const float* Wq = (const float*)d_in[7];
    const float* bq = (const float*)d_in[8];
    const float* Wk = (const float*)d_in[9];
    const float* bk = (const float*)d_in[10];
    const float* Wv = (const float*)d_in[11];
    const float* bv = (const float*)d_in[12];
    const float* Wo = (const float*)d_in[13];
    const float* bo = (const float*)d_in[14];
    const float* gamma = (const float*)d_in[15];
    const float* beta = (const float*)d_in[16];

    const size_t nsd = (size_t)Ndim * Sdim * Ddim;  // 4,194,304
    const size_t nss = (size_t)Ndim * Sdim * Sdim;  // 67,108,864
    unsigned short* qh = (unsigned short*)d_ws;     // bf16 [n][s][d]
    unsigned short* kh = qh + nsd;                  // bf16 [n][s][d]
    unsigned short* vh = kh + nsd;                  // bf16 [n][s][d]
    unsigned short* vt = vh + nsd;                  // bf16 [n][d][s]
    float* ctx = (float*)(vt + nsd);                // fp32 [s*B][E]
    float* attn = ctx + nsd;                        // fp32 [n][i][j]
    int* flag = (int*)(attn + nss);
    unsigned short* P = (unsigned short*)((char*)flag + 16);  // bf16 [n][i][j]
    float* xb = (float*)d_out;

    const size_t base_bytes = 4 * nsd * 2 + nsd * 4 + nss * 4 + 16;
    const int pmode = (ws_size >= base_bytes + nss * 2) ? 1 : 0;

    detect_mask<<<1, 256, 0, stream>>>((const unsigned int*)mask, flag);

    dim3 gp(Mdim / 64, Edim / 64);
    proj_gemm<0><<<gp, 256, 0, stream>>>(query, Wq, bq, nullptr, qh);
    proj_gemm<0><<<gp, 256, 0, stream>>>(key, Wk, bk, nullptr, kh);
    proj_gemm<0><<<gp, 256, 0, stream>>>(value, Wv, bv, nullptr, vh);
    transpose_v<<<dim3(Sdim / 64, Ndim), 256, 0, stream>>>(vh, vt);

    logits_mfma<<<dim3(Sdim / 16, Sdim / 16), 256, 0, stream>>>(qh, kh, ek, mask, flag, attn);

    if (pmode) {
        softmax_kernel<1><<<dim3(Ndim * Sdim), 256, 0, stream>>>(attn, P);
        pv_v_mfma<1><<<dim3(Ndim, Sdim / 64), 256, 0, stream>>>(P, vt, ctx);
        pv_ev_mfma<1><<<dim3(Sdim), 256, 0, stream>>>(P, evl, ctx);
    } else {
        softmax_kernel<0><<<dim3(Ndim * Sdim), 256, 0, stream>>>(attn, nullptr);
        pv_v_mfma<0><<<dim3(Ndim, Sdim / 64), 256, 0, stream>>>(attn, vt, ctx);
        pv_ev_mfma<0><<<dim3(Sdim), 256, 0, stream>>>(attn, evl, ctx);
    }

    proj_gemm<1><<<gp, 256, 0, stream>>>(ctx, Wo, bo, query, xb);
    ln_kernel<<<dim3(Mdim), 256, 0, stream>>>(xb, gamma, beta);
}